// Round 1
// 363.287 us; speedup vs baseline: 1.0776x; 1.0776x over previous
//
#include <hip/hip_runtime.h>
#include <hip/hip_bf16.h>
#include <math.h>

#define B_ 16
#define S_ 2048
#define DM_ 64
#define HD_ 1024

typedef float floatx4 __attribute__((ext_vector_type(4)));

// ---------------------------------------------------------------------------
// Algebraic refactor (unchanged):
//   logits = (x Wq)(x Wk)^T = x M x^T,  M = Wq Wk^T (64x64)
//   out    = softmax(mask(logits/4)) @ (x Wv) = (P @ x) @ Wv
// Attention path fully fp32 (absmax headroom vs 0.139 threshold).
//
// R(this): k_attn2 -> k_attn3.
//   * Root cause of 207us: occupancy 14.4%. Heavy+light block pairing leaves
//     the CU at 4 waves for ~31 of 32 tiles once the light block drains.
//   * Fix: intra-block split-K. 512-thread block = two 256-thread halves;
//     half A does first ceil(T/2) key-tiles, half B the rest, private
//     x_t/x_r/P_t per half, shared y_t; flash-merge (m,l,U) via LDS at end.
//     Max 16 tiles/block, blocks ordered heavy-first (qt ascending) for
//     LPT backfill; 8 uniform waves/CU for the block's whole lifetime.
//   * LDS writes vectorized: x staged via in-register 4x4 transpose (pure
//     ds_write_b128, bank-uniform), P_t written as 4x b128 (kills the
//     8-way scalar-store conflicts -> expect SQ_LDS_BANK_CONFLICT < 1M).
//   * psum butterfly removed: per-lane lsum carried through alpha chain,
//     single 4-stage reduce at the end (-16 ds_bpermute/thread/tile).
//   * Next x-tile prefetched into registers after the stage barrier
//     (in flight across QK; covers L2 latency at 1 block/CU).
// ---------------------------------------------------------------------------

// K1: M[d][e] = sum_f W[d][f] * W[e][1024+f]   (Wq row d . Wk row e)
__global__ void k_M(const float* __restrict__ W, float* __restrict__ M) {
    const int d = blockIdx.x;     // 0..63
    const int e = threadIdx.x;    // 0..63
    const floatx4* wq = (const floatx4*)(W + (size_t)d * 3072);
    const floatx4* wk = (const floatx4*)(W + (size_t)e * 3072 + 1024);
    floatx4 a = {0.f, 0.f, 0.f, 0.f};
    for (int j = 0; j < 256; ++j) {
        floatx4 qv = wq[j], kv = wk[j];
        a.x = fmaf(qv.x, kv.x, a.x);
        a.y = fmaf(qv.y, kv.y, a.y);
        a.z = fmaf(qv.z, kv.z, a.z);
        a.w = fmaf(qv.w, kv.w, a.w);
    }
    M[d * 64 + e] = (a.x + a.y) + (a.z + a.w);
}

// K2: y = x @ M   [32768 x 64] @ [64 x 64], fp32. (unchanged)
__global__ __launch_bounds__(256, 2) void k_y(
        const float* __restrict__ x, const float* __restrict__ M,
        float* __restrict__ y) {
    __shared__ __align__(16) float xs[128 * 64];
    const int tid = threadIdx.x;
    const int c   = tid & 63;
    const int g   = tid >> 6;
    const int r0  = blockIdx.x * 128;

    {
        const floatx4* src = (const floatx4*)(x + (size_t)r0 * 64);
        floatx4* dst = (floatx4*)xs;
#pragma unroll
        for (int i = 0; i < 8; ++i) dst[tid * 8 + i] = src[tid * 8 + i];
    }
    float mreg[64];
#pragma unroll
    for (int d = 0; d < 64; ++d) mreg[d] = M[d * 64 + c];
    __syncthreads();

    for (int r = 0; r < 32; ++r) {
        const int row = g * 32 + r;
        const floatx4* xr = (const floatx4*)(xs + row * 64);
        float a0 = 0.f, a1 = 0.f, a2 = 0.f, a3 = 0.f;
#pragma unroll
        for (int j = 0; j < 16; ++j) {
            floatx4 xv = xr[j];
            a0 = fmaf(xv.x, mreg[4 * j + 0], a0);
            a1 = fmaf(xv.y, mreg[4 * j + 1], a1);
            a2 = fmaf(xv.z, mreg[4 * j + 2], a2);
            a3 = fmaf(xv.w, mreg[4 * j + 3], a3);
        }
        y[(size_t)(r0 + row) * 64 + c] = (a0 + a1) + (a2 + a3);
    }
}

// K3: flash attention, fp32, intra-block split-K (2 halves of 256 threads).
// Block = 64 query rows of one batch; per-half key tiles of 64.
// Within a half: qi=lt>>4 owns rows qi*4..+3, ki=lt&15 owns keys ki*4..+3.
// NOTE: keep all register-tile loops fully unrolled (dynamic index -> scratch).
__global__ __launch_bounds__(512, 2) void k_attn3(
        const float* __restrict__ xg, const float* __restrict__ yg,
        float* __restrict__ Un) {
    __shared__ __align__(16) float y_t[64 * 68];        // [d][q]  shared
    __shared__ __align__(16) float x_t[2 * 64 * 68];    // [d][key] per half
    __shared__ __align__(16) float x_r[2 * 64 * 68];    // [key][d] per half
    __shared__ __align__(16) float P_t[2 * 64 * 68];    // [key][q] per half
    // 7 * 17408 B = 121,856 B -> 1 block/CU (by design; 8 uniform waves)

    const int tid = threadIdx.x;        // 0..511
    const int h   = tid >> 8;           // half: 0 = first kt range, 1 = second
    const int lt  = tid & 255;
    const int qi  = lt >> 4;            // 0..15
    const int ki  = lt & 15;            // 0..15

    const int bid = blockIdx.x;
    const int qt  = bid >> 4;           // 0..31, heavy (qt=0) dispatched first
    const int bb  = bid & 15;
    const int q0  = qt * 64;
    const int T   = 32 - qt;            // total key tiles for this q-tile
    const int nA  = (T + 1) >> 1;       // tiles for half A
    const int nOwn = h ? (T - nA) : nA; // may be 0 for half B when T == 1
    const int kt0  = q0 + (h ? nA * 64 : 0);

    float* xt = x_t + h * 4352;
    float* xr = x_r + h * 4352;
    float* Pt = P_t + h * 4352;

    // ---- stage y tile -> y_t[d][q] (once per block, all 512 threads) ----
    {
        const int qrow = tid >> 3, part = tid & 7;
        const float* src = yg + ((size_t)bb * S_ + q0 + qrow) * 64 + part * 8;
        floatx4 v0 = *(const floatx4*)(src);
        floatx4 v1 = *(const floatx4*)(src + 4);
#pragma unroll
        for (int e = 0; e < 4; ++e) {
            y_t[(part * 8 + e) * 68 + qrow]       = v0[e];
            y_t[(part * 8 + 4 + e) * 68 + qrow]   = v1[e];
        }
    }

    float U[4][4], m[4], lsum[4];
#pragma unroll
    for (int r = 0; r < 4; ++r) {
        m[r] = -INFINITY; lsum[r] = 0.f;
#pragma unroll
        for (int c = 0; c < 4; ++c) U[r][c] = 0.f;
    }

    const float* xb = xg + (size_t)bb * S_ * 64;

    // staging roles: kg (4 keys each) = qi, dc (d-chunk) = ki
    const int kg = qi, dc = ki;

    // prefetch tile 0 into registers
    floatx4 v0, v1, v2, v3;
    if (0 < nOwn) {
        const float* sp = xb + (size_t)(kt0 + kg * 4) * 64 + dc * 4;
        v0 = *(const floatx4*)(sp);
        v1 = *(const floatx4*)(sp + 64);
        v2 = *(const floatx4*)(sp + 128);
        v3 = *(const floatx4*)(sp + 192);
    }

    for (int t = 0; t < nA; ++t) {
        const int kt = kt0 + t * 64;
        __syncthreads();   // prev tile readers done with x_r/x_t/P_t
        if (t < nOwn) {
            // x_r[key][d]: direct b128 (bank-slot (4kg+i+dc)%8: uniform 8/slot)
            *(floatx4*)(xr + (kg * 4 + 0) * 68 + dc * 4) = v0;
            *(floatx4*)(xr + (kg * 4 + 1) * 68 + dc * 4) = v1;
            *(floatx4*)(xr + (kg * 4 + 2) * 68 + dc * 4) = v2;
            *(floatx4*)(xr + (kg * 4 + 3) * 68 + dc * 4) = v3;
            // x_t[d][key]: in-register 4x4 transpose, b128 writes
#pragma unroll
            for (int e = 0; e < 4; ++e) {
                floatx4 w = {v0[e], v1[e], v2[e], v3[e]};
                *(floatx4*)(xt + (dc * 4 + e) * 68 + kg * 4) = w;
            }
        }
        __syncthreads();

        // prefetch next tile now: loads stay in flight across QK+softmax,
        // drained at the P-visibility barrier (covers L2 latency @1 block/CU)
        if (t + 1 < nOwn) {
            const float* sp = xb + (size_t)(kt + 64 + kg * 4) * 64 + dc * 4;
            v0 = *(const floatx4*)(sp);
            v1 = *(const floatx4*)(sp + 64);
            v2 = *(const floatx4*)(sp + 128);
            v3 = *(const floatx4*)(sp + 192);
        }

        if (t < nOwn) {
            // ---- QK: s[4][4] = y_tile(rows) . x_tile(keys), K=64 ----
            float s[4][4];
#pragma unroll
            for (int r = 0; r < 4; ++r)
#pragma unroll
                for (int c = 0; c < 4; ++c) s[r][c] = 0.f;
#pragma unroll 8
            for (int kk = 0; kk < 64; ++kk) {
                floatx4 a = *(const floatx4*)(y_t + kk * 68 + qi * 4);
                floatx4 b = *(const floatx4*)(xt + kk * 68 + ki * 4);
#pragma unroll
                for (int r = 0; r < 4; ++r)
#pragma unroll
                    for (int c = 0; c < 4; ++c) s[r][c] = fmaf(a[r], b[c], s[r][c]);
            }

            // ---- scale + faithful mask + online softmax (deferred l) ----
            float p[4][4], alpha[4];
#pragma unroll
            for (int r = 0; r < 4; ++r) {
                const int ig = q0 + qi * 4 + r;
                float rmax = -INFINITY;
#pragma unroll
                for (int c = 0; c < 4; ++c) {
                    const int jg = kt + ki * 4 + c;
                    float v = s[r][c] * 0.25f;
                    if (jg < ig || v == 0.0f) v = -9.0e15f;  // triu + (==0 -> -9e15)
                    s[r][c] = v;
                    rmax = fmaxf(rmax, v);
                }
                rmax = fmaxf(rmax, __shfl_xor(rmax, 1));
                rmax = fmaxf(rmax, __shfl_xor(rmax, 2));
                rmax = fmaxf(rmax, __shfl_xor(rmax, 4));
                rmax = fmaxf(rmax, __shfl_xor(rmax, 8));
                const float mnew = fmaxf(m[r], rmax);
                alpha[r] = __expf(m[r] - mnew);            // first tile: exp(-inf)=0
                float ps = 0.f;
#pragma unroll
                for (int c = 0; c < 4; ++c) {
                    const float pv = __expf(s[r][c] - mnew);
                    p[r][c] = pv;
                    ps += pv;
                }
                m[r] = mnew;
                lsum[r] = lsum[r] * alpha[r] + ps;         // per-lane partial; reduce at end
            }

            // P -> LDS transposed, b128: P_t[key][qi*4..+3] = {p[0..3][c]}
            // bank-slot (4ki+c+qi)%8: uniform 8/slot (was 16 scalar 8-way stores)
#pragma unroll
            for (int c = 0; c < 4; ++c) {
                floatx4 vv = {p[0][c], p[1][c], p[2][c], p[3][c]};
                *(floatx4*)(Pt + (ki * 4 + c) * 68 + qi * 4) = vv;
            }

            // rescale U
#pragma unroll
            for (int r = 0; r < 4; ++r)
#pragma unroll
                for (int c = 0; c < 4; ++c) U[r][c] *= alpha[r];
        }

        __syncthreads();   // P_t visible; also orders x reuse

        if (t < nOwn) {
            // ---- PX: U[q][d] += P[q][j] * x[j][d], K=64 keys ----
#pragma unroll 8
            for (int j = 0; j < 64; ++j) {
                floatx4 a = *(const floatx4*)(Pt + j * 68 + qi * 4);
                floatx4 b = *(const floatx4*)(xr + j * 68 + ki * 4);
#pragma unroll
                for (int r = 0; r < 4; ++r)
#pragma unroll
                    for (int c = 0; c < 4; ++c) U[r][c] = fmaf(a[r], b[c], U[r][c]);
            }
        }
    }

    // ---- finalize per-half l: one 4-stage butterfly over the 16-lane group
    float lf[4];
#pragma unroll
    for (int r = 0; r < 4; ++r) {
        float s2 = lsum[r];
        s2 += __shfl_xor(s2, 1);
        s2 += __shfl_xor(s2, 2);
        s2 += __shfl_xor(s2, 4);
        s2 += __shfl_xor(s2, 8);
        lf[r] = s2;
    }

    // ---- merge halves (flash combine) via LDS scratch, then write Un ----
    __syncthreads();                     // all compute done; x_t free
    float* scratch = x_t;                // 256 threads * 28 floats (24 used)
    if (h == 1) {
        float* bp = scratch + lt * 28;   // stride 28 -> 7lt%8 spans all bank slots
        *(floatx4*)(bp)     = (floatx4){m[0], m[1], m[2], m[3]};
        *(floatx4*)(bp + 4) = (floatx4){lf[0], lf[1], lf[2], lf[3]};
#pragma unroll
        for (int r = 0; r < 4; ++r)
            *(floatx4*)(bp + 8 + 4 * r) =
                (floatx4){U[r][0], U[r][1], U[r][2], U[r][3]};
    }
    __syncthreads();
    if (h == 0) {
        const float* bp = scratch + lt * 28;
        floatx4 mB = *(const floatx4*)(bp);
        floatx4 lB = *(const floatx4*)(bp + 4);
#pragma unroll
        for (int r = 0; r < 4; ++r) {
            floatx4 UB = *(const floatx4*)(bp + 8 + 4 * r);
            const float mT  = fmaxf(m[r], mB[r]);          // m[r] finite (A has tile 0)
            const float eA  = __expf(m[r] - mT);
            const float eB  = __expf(mB[r] - mT);          // empty B: exp(-inf)=0
            const float lT  = lf[r] * eA + lB[r] * eB;
            const float inv = 1.0f / lT;
            floatx4 v;
#pragma unroll
            for (int c = 0; c < 4; ++c)
                v[c] = (U[r][c] * eA + UB[c] * eB) * inv;
            *(floatx4*)(Un + ((size_t)bb * S_ + q0 + qi * 4 + r) * 64 + ki * 4) = v;
        }
    }
}

// K4: out = Un @ Wv   [32768 x 64] @ [64 x 1024] -> fp32 out. (unchanged)
__global__ __launch_bounds__(256, 2) void k_out(
        const float* __restrict__ Un, const float* __restrict__ W,
        float* __restrict__ out) {
    __shared__ __align__(16) float us[64 * 64];
    const int tid = threadIdx.x;
    const int r0  = (blockIdx.x >> 1) * 64;
    const int cb  = (blockIdx.x & 1) * 512;
    const int c0  = cb + tid;

    float w0[64], w1[64];
#pragma unroll
    for (int d = 0; d < 64; ++d) {
        w0[d] = W[(size_t)d * 3072 + 2048 + c0];
        w1[d] = W[(size_t)d * 3072 + 2048 + c0 + 256];
    }
    {
        const floatx4* src = (const floatx4*)(Un + (size_t)r0 * 64);
        floatx4* dst = (floatx4*)us;
#pragma unroll
        for (int i = 0; i < 4; ++i) dst[tid * 4 + i] = src[tid * 4 + i];
    }
    __syncthreads();

    for (int row = 0; row < 64; ++row) {
        const floatx4* ur = (const floatx4*)(us + row * 64);
        float a0 = 0.f, a1 = 0.f;
#pragma unroll
        for (int j = 0; j < 16; ++j) {
            floatx4 u = ur[j];
            a0 = fmaf(u.x, w0[4 * j + 0], a0); a1 = fmaf(u.x, w1[4 * j + 0], a1);
            a0 = fmaf(u.y, w0[4 * j + 1], a0); a1 = fmaf(u.y, w1[4 * j + 1], a1);
            a0 = fmaf(u.z, w0[4 * j + 2], a0); a1 = fmaf(u.z, w1[4 * j + 2], a1);
            a0 = fmaf(u.w, w0[4 * j + 3], a0); a1 = fmaf(u.w, w1[4 * j + 3], a1);
        }
        float* op = out + (size_t)(r0 + row) * HD_ + c0;
        op[0]   = a0;
        op[256] = a1;
    }
}

extern "C" void kernel_launch(void* const* d_in, const int* in_sizes, int n_in,
                              void* d_out, int out_size, void* d_ws, size_t ws_size,
                              hipStream_t stream) {
    const float* x = (const float*)d_in[0];
    const float* W = (const float*)d_in[1];
    float* out = (float*)d_out;

    float* M  = (float*)d_ws;                 // 64*64
    float* y  = M + 4096;                     // 32768*64
    float* Un = y + (size_t)32768 * 64;       // 32768*64   (~16.8 MB total)

    k_M    <<<dim3(64),   64,  0, stream>>>(W, M);
    k_y    <<<dim3(256),  256, 0, stream>>>(x, M, y);
    k_attn3<<<dim3(512),  512, 0, stream>>>(x, y, Un);
    k_out  <<<dim3(1024), 256, 0, stream>>>(Un, W, out);
}

// Round 2
// 264.635 us; speedup vs baseline: 1.4794x; 1.3728x over previous
//
#include <hip/hip_runtime.h>
#include <math.h>

#define B_ 16
#define S_ 2048
#define DM_ 64
#define HD_ 1024

typedef float floatx4 __attribute__((ext_vector_type(4)));
typedef short bf16x8 __attribute__((ext_vector_type(8)));
typedef unsigned short ushort4v __attribute__((ext_vector_type(4)));
typedef unsigned short ushort8v __attribute__((ext_vector_type(8)));

// ---------------------------------------------------------------------------
// Algebraic refactor (unchanged):
//   logits = (x Wq)(x Wk)^T = x M x^T,  M = Wq Wk^T (64x64)
//   out    = softmax(mask(logits/4)) @ (x Wv) = (P @ x) @ Wv
//
// R2: k_attn3 -> k_attn4. fp32 FMA floor was 56us of the 171us (VALUBusy 55%,
// MfmaUtil 0). Move QK/PX to mfma_f32_16x16x32_bf16 with split-bf16 fp32
// emulation:
//   QK 3-term: yh*xh + yh*xl + yl*xh  (logit err ~2^-17; exp-safe)
//   PX 2-term: Phi*xh + Phi*xl        (err <= 2^-9 on convex comb of x)
// Fragment mapping (guide-verified): A[row=l%16][k=8*(l>>4)+j] contiguous,
// B[k=8*(l>>4)+j][col=l%16], C/D[row=4*(l>>4)+r][col=l%16].
// LDS rows padded to 72 bf16 (144 B) -> b128 frag reads bank-clean.
// x_t transposed writes get 16B-block XOR swizzle (blk ^= (row>>3)&3),
// verified conflict-free per 8-lane phase. P is per-wave-private (16x72,
// written b16 2-way-free, read back as A-frags; no extra barrier).
// Block structure from R1 kept: 512 thr = 2 split-K halves, heavy-first,
// flash merge via LDS scratch. 2 barriers/tile. LDS 110.6 KB -> 1 blk/CU.
// ---------------------------------------------------------------------------

__device__ __forceinline__ unsigned short bf_hi(float f) {
    return (unsigned short)((__float_as_uint(f) + 0x8000u) >> 16);   // RNE-ish
}
__device__ __forceinline__ float bf_f(unsigned short h) {
    return __uint_as_float((unsigned)h << 16);
}
__device__ __forceinline__ void cvt4(floatx4 v, ushort4v& h, ushort4v& l) {
    h[0] = bf_hi(v.x); l[0] = bf_hi(v.x - bf_f(h[0]));
    h[1] = bf_hi(v.y); l[1] = bf_hi(v.y - bf_f(h[1]));
    h[2] = bf_hi(v.z); l[2] = bf_hi(v.z - bf_f(h[2]));
    h[3] = bf_hi(v.w); l[3] = bf_hi(v.w - bf_f(h[3]));
}

#define MFMA(a, b, c) __builtin_amdgcn_mfma_f32_16x16x32_bf16((a), (b), (c), 0, 0, 0)

// K1: M[d][e] = Wq row d . Wk row e   (unchanged)
__global__ void k_M(const float* __restrict__ W, float* __restrict__ M) {
    const int d = blockIdx.x;
    const int e = threadIdx.x;
    const floatx4* wq = (const floatx4*)(W + (size_t)d * 3072);
    const floatx4* wk = (const floatx4*)(W + (size_t)e * 3072 + 1024);
    floatx4 a = {0.f, 0.f, 0.f, 0.f};
    for (int j = 0; j < 256; ++j) {
        floatx4 qv = wq[j], kv = wk[j];
        a.x = fmaf(qv.x, kv.x, a.x);
        a.y = fmaf(qv.y, kv.y, a.y);
        a.z = fmaf(qv.z, kv.z, a.z);
        a.w = fmaf(qv.w, kv.w, a.w);
    }
    M[d * 64 + e] = (a.x + a.y) + (a.z + a.w);
}

// K2: y = x @ M   (unchanged)
__global__ __launch_bounds__(256, 2) void k_y(
        const float* __restrict__ x, const float* __restrict__ M,
        float* __restrict__ y) {
    __shared__ __align__(16) float xs[128 * 64];
    const int tid = threadIdx.x;
    const int c   = tid & 63;
    const int g   = tid >> 6;
    const int r0  = blockIdx.x * 128;

    {
        const floatx4* src = (const floatx4*)(x + (size_t)r0 * 64);
        floatx4* dst = (floatx4*)xs;
#pragma unroll
        for (int i = 0; i < 8; ++i) dst[tid * 8 + i] = src[tid * 8 + i];
    }
    float mreg[64];
#pragma unroll
    for (int d = 0; d < 64; ++d) mreg[d] = M[d * 64 + c];
    __syncthreads();

    for (int r = 0; r < 32; ++r) {
        const int row = g * 32 + r;
        const floatx4* xr = (const floatx4*)(xs + row * 64);
        float a0 = 0.f, a1 = 0.f, a2 = 0.f, a3 = 0.f;
#pragma unroll
        for (int j = 0; j < 16; ++j) {
            floatx4 xv = xr[j];
            a0 = fmaf(xv.x, mreg[4 * j + 0], a0);
            a1 = fmaf(xv.y, mreg[4 * j + 1], a1);
            a2 = fmaf(xv.z, mreg[4 * j + 2], a2);
            a3 = fmaf(xv.w, mreg[4 * j + 3], a3);
        }
        y[(size_t)(r0 + row) * 64 + c] = (a0 + a1) + (a2 + a3);
    }
}

// K3: flash attention, split-bf16 MFMA, intra-block split-K (2x256 halves).
// Per half: 4 waves, wave w owns q-strip rows [16w,16w+16); per tile:
// QK 24 mfma + PX 16 mfma per wave. Softmax in C-frag layout:
// lane holds S[q=4*lg+r][key=lm+16c]; row-reduce = shfl_xor(1,2,4,8).
__global__ __launch_bounds__(512, 2) void k_attn4(
        const float* __restrict__ xg, const float* __restrict__ yg,
        float* __restrict__ Un) {
    // carve one LDS block: per half {xr_h, xr_l, xt_h, xt_l, P} [64][72] bf16,
    // shared {y_h, y_l} [64][72]. 55296 shorts = 110,592 B.
    __shared__ __align__(16) unsigned short sm[55296];

    const int tid  = threadIdx.x;          // 0..511
    const int h    = tid >> 8;             // half
    const int lt   = tid & 255;
    const int w    = lt >> 6;              // wave in half, 0..3
    const int lane = tid & 63;
    const int lm   = lane & 15;            // frag row/col select
    const int lg   = lane >> 4;            // k-group 0..3

    const int bid = blockIdx.x;
    const int qt  = bid >> 4;              // heavy-first (qt=0 has T=32)
    const int bb  = bid & 15;
    const int q0  = qt * 64;
    const int T   = 32 - qt;
    const int nA  = (T + 1) >> 1;
    const int nOwn = h ? (T - nA) : nA;
    const int kt0  = q0 + (h ? nA * 64 : 0);

    unsigned short* base = sm + h * 23040;
    unsigned short* xrh = base;                         // x row-major hi
    unsigned short* xrl = base + 4608;                  // x row-major lo
    unsigned short* xth = base + 9216;                  // x transposed hi (swz)
    unsigned short* xtl = base + 13824;                 // x transposed lo (swz)
    unsigned short* Pw  = base + 18432 + w * 1152;      // per-wave P [16][72]
    unsigned short* yh  = sm + 46080;
    unsigned short* yl  = sm + 50688;

    // ---- stage y tile -> y_h/y_l [q][d], split-bf16 (512 threads) ----
    {
        const int qrow = tid >> 3, part = tid & 7;
        const float* src = yg + ((size_t)bb * S_ + q0 + qrow) * 64 + part * 8;
        floatx4 a = *(const floatx4*)(src);
        floatx4 b = *(const floatx4*)(src + 4);
        ushort4v ha, la, hb, lb;
        cvt4(a, ha, la); cvt4(b, hb, lb);
        ushort8v hv = {ha[0], ha[1], ha[2], ha[3], hb[0], hb[1], hb[2], hb[3]};
        ushort8v lv = {la[0], la[1], la[2], la[3], lb[0], lb[1], lb[2], lb[3]};
        *(ushort8v*)(yh + qrow * 72 + part * 8) = hv;
        *(ushort8v*)(yl + qrow * 72 + part * 8) = lv;
    }

    const float* xb = xg + (size_t)bb * S_ * 64;
    const int kg = lt >> 4, dc = lt & 15;   // staging roles: keys 4kg..+3, d 4dc..+3

    // prefetch tile 0
    floatx4 v0, v1, v2, v3;
    if (0 < nOwn) {
        const float* sp = xb + (size_t)(kt0 + kg * 4) * 64 + dc * 4;
        v0 = *(const floatx4*)(sp);
        v1 = *(const floatx4*)(sp + 64);
        v2 = *(const floatx4*)(sp + 128);
        v3 = *(const floatx4*)(sp + 192);
    }

    __syncthreads();   // y staged

    // hoist y A-frags (loop-invariant): rows 16w+lm, k = 32*kc + 8*lg + j
    bf16x8 aqh[2], aql[2];
#pragma unroll
    for (int kc = 0; kc < 2; ++kc) {
        const int off = (16 * w + lm) * 72 + 32 * kc + 8 * lg;
        aqh[kc] = *(const bf16x8*)(yh + off);
        aql[kc] = *(const bf16x8*)(yl + off);
    }

    floatx4 U[4];                 // U[c][r] = U[q=4lg+r][d=lm+16c]
    float m[4], lsum[4];
#pragma unroll
    for (int r = 0; r < 4; ++r) { m[r] = -INFINITY; lsum[r] = 0.f; }
#pragma unroll
    for (int c = 0; c < 4; ++c) U[c] = (floatx4){0.f, 0.f, 0.f, 0.f};

    for (int t = 0; t < nA; ++t) {
        const int kt = kt0 + t * 64;
        __syncthreads();   // prev tile readers done with xr/xt
        if (t < nOwn) {
            ushort4v h0, l0, h1, l1, h2, l2, h3, l3;
            cvt4(v0, h0, l0); cvt4(v1, h1, l1);
            cvt4(v2, h2, l2); cvt4(v3, h3, l3);
            // xr[key][d]: rows 4kg+i, cols 4dc (b64, conflict-free)
            *(ushort4v*)(xrh + (4 * kg + 0) * 72 + 4 * dc) = h0;
            *(ushort4v*)(xrh + (4 * kg + 1) * 72 + 4 * dc) = h1;
            *(ushort4v*)(xrh + (4 * kg + 2) * 72 + 4 * dc) = h2;
            *(ushort4v*)(xrh + (4 * kg + 3) * 72 + 4 * dc) = h3;
            *(ushort4v*)(xrl + (4 * kg + 0) * 72 + 4 * dc) = l0;
            *(ushort4v*)(xrl + (4 * kg + 1) * 72 + 4 * dc) = l1;
            *(ushort4v*)(xrl + (4 * kg + 2) * 72 + 4 * dc) = l2;
            *(ushort4v*)(xrl + (4 * kg + 3) * 72 + 4 * dc) = l3;
            // xt[d][key]: in-reg 4x4 transpose; 16B-block XOR swizzle on col
#pragma unroll
            for (int e = 0; e < 4; ++e) {
                ushort4v th = {h0[e], h1[e], h2[e], h3[e]};
                ushort4v tl = {l0[e], l1[e], l2[e], l3[e]};
                const int rT  = 4 * dc + e;
                const int off = rT * 72 + (((kg >> 1) ^ ((rT >> 3) & 3)) << 3)
                              + ((kg & 1) << 2);
                *(ushort4v*)(xth + off) = th;
                *(ushort4v*)(xtl + off) = tl;
            }
        }
        __syncthreads();

        // prefetch next tile (in flight across QK+softmax+PX)
        if (t + 1 < nOwn) {
            const float* sp = xb + (size_t)(kt + 64 + kg * 4) * 64 + dc * 4;
            v0 = *(const floatx4*)(sp);
            v1 = *(const floatx4*)(sp + 64);
            v2 = *(const floatx4*)(sp + 128);
            v3 = *(const floatx4*)(sp + 192);
        }

        if (t < nOwn) {
            // ---- QK: 3-term split, 24 mfma ----
            floatx4 Sc[4] = {{0.f,0.f,0.f,0.f},{0.f,0.f,0.f,0.f},
                             {0.f,0.f,0.f,0.f},{0.f,0.f,0.f,0.f}};
#pragma unroll
            for (int kc = 0; kc < 2; ++kc) {
#pragma unroll
                for (int c = 0; c < 4; ++c) {
                    const int ro = (lm + 16 * c) * 72 + 32 * kc + 8 * lg;
                    bf16x8 bh = *(const bf16x8*)(xrh + ro);
                    bf16x8 bl = *(const bf16x8*)(xrl + ro);
                    Sc[c] = MFMA(aqh[kc], bh, Sc[c]);
                    Sc[c] = MFMA(aqh[kc], bl, Sc[c]);
                    Sc[c] = MFMA(aql[kc], bh, Sc[c]);
                }
            }

            // ---- scale + faithful mask + online softmax ----
            float p[4][4], alpha[4];
#pragma unroll
            for (int r = 0; r < 4; ++r) {
                const int ig = q0 + 16 * w + 4 * lg + r;
                float sv[4];
                float rmax = -INFINITY;
#pragma unroll
                for (int c = 0; c < 4; ++c) {
                    const int jg = kt + lm + 16 * c;
                    float v = Sc[c][r] * 0.25f;
                    if (jg < ig || v == 0.0f) v = -9.0e15f;   // triu + (==0 -> -9e15)
                    sv[c] = v;
                    rmax = fmaxf(rmax, v);
                }
                rmax = fmaxf(rmax, __shfl_xor(rmax, 1));
                rmax = fmaxf(rmax, __shfl_xor(rmax, 2));
                rmax = fmaxf(rmax, __shfl_xor(rmax, 4));
                rmax = fmaxf(rmax, __shfl_xor(rmax, 8));
                const float mnew = fmaxf(m[r], rmax);
                alpha[r] = __expf(m[r] - mnew);               // first tile: 0
                float ps = 0.f;
#pragma unroll
                for (int c = 0; c < 4; ++c) {
                    const float pv = __expf(sv[c] - mnew);
                    p[r][c] = pv;
                    ps += pv;
                }
                m[r] = mnew;
                lsum[r] = lsum[r] * alpha[r] + ps;            // per-lane partial
            }

            // P -> per-wave LDS (bf16 hi), rows strip-local; b16 2-way-free
#pragma unroll
            for (int r = 0; r < 4; ++r)
#pragma unroll
                for (int c = 0; c < 4; ++c)
                    Pw[(4 * lg + r) * 72 + lm + 16 * c] = bf_hi(p[r][c]);

            // rescale U
            floatx4 av = {alpha[0], alpha[1], alpha[2], alpha[3]};
#pragma unroll
            for (int c = 0; c < 4; ++c) U[c] *= av;

            // ---- PX: 2-term, 16 mfma (P private to wave: no barrier) ----
#pragma unroll
            for (int kc = 0; kc < 2; ++kc) {
                bf16x8 ap = *(const bf16x8*)(Pw + lm * 72 + 32 * kc + 8 * lg);
#pragma unroll
                for (int c = 0; c < 4; ++c) {
                    const int d   = lm + 16 * c;
                    const int blk = (4 * kc + lg) ^ ((d >> 3) & 3);
                    const int off = d * 72 + blk * 8;
                    bf16x8 bh = *(const bf16x8*)(xth + off);
                    bf16x8 bl = *(const bf16x8*)(xtl + off);
                    U[c] = MFMA(ap, bh, U[c]);
                    U[c] = MFMA(ap, bl, U[c]);
                }
            }
        }
    }

    // ---- finalize per-half l: one butterfly over the 16-lane group ----
    float lf[4];
#pragma unroll
    for (int r = 0; r < 4; ++r) {
        float s2 = lsum[r];
        s2 += __shfl_xor(s2, 1);
        s2 += __shfl_xor(s2, 2);
        s2 += __shfl_xor(s2, 4);
        s2 += __shfl_xor(s2, 8);
        lf[r] = s2;
    }

    // ---- merge halves (flash combine) via LDS scratch; half A writes Un ----
    __syncthreads();                       // all compute done; x buffers free
    float* sc = (float*)sm;                // 256 * 24 floats = 24.6 KB
    if (h == 1) {
        float* bp = sc + lt * 24;
        *(floatx4*)(bp)     = (floatx4){m[0], m[1], m[2], m[3]};
        *(floatx4*)(bp + 4) = (floatx4){lf[0], lf[1], lf[2], lf[3]};
#pragma unroll
        for (int c = 0; c < 4; ++c) *(floatx4*)(bp + 8 + 4 * c) = U[c];
    }
    __syncthreads();
    if (h == 0) {
        const float* bp = sc + lt * 24;
        floatx4 mB = *(const floatx4*)(bp);
        floatx4 lB = *(const floatx4*)(bp + 4);
        floatx4 UB[4];
#pragma unroll
        for (int c = 0; c < 4; ++c) UB[c] = *(const floatx4*)(bp + 8 + 4 * c);
        float eA[4], eB[4], inv[4];
#pragma unroll
        for (int r = 0; r < 4; ++r) {
            const float mT = fmaxf(m[r], mB[r]);   // m finite (A has tile 0)
            eA[r] = __expf(m[r] - mT);
            eB[r] = __expf(mB[r] - mT);            // empty B: exp(-inf)=0
            const float lT = lf[r] * eA[r] + lB[r] * eB[r];
            inv[r] = 1.0f / lT;
        }
#pragma unroll
        for (int r = 0; r < 4; ++r) {
            const size_t row = (size_t)bb * S_ + q0 + 16 * w + 4 * lg + r;
#pragma unroll
            for (int c = 0; c < 4; ++c)
                Un[row * 64 + lm + 16 * c] =
                    (U[c][r] * eA[r] + UB[c][r] * eB[r]) * inv[r];
        }
    }
}

// K4: out = Un @ Wv   (unchanged)
__global__ __launch_bounds__(256, 2) void k_out(
        const float* __restrict__ Un, const float* __restrict__ W,
        float* __restrict__ out) {
    __shared__ __align__(16) float us[64 * 64];
    const int tid = threadIdx.x;
    const int r0  = (blockIdx.x >> 1) * 64;
    const int cb  = (blockIdx.x & 1) * 512;
    const int c0  = cb + tid;

    float w0[64], w1[64];
#pragma unroll
    for (int d = 0; d < 64; ++d) {
        w0[d] = W[(size_t)d * 3072 + 2048 + c0];
        w1[d] = W[(size_t)d * 3072 + 2048 + c0 + 256];
    }
    {
        const floatx4* src = (const floatx4*)(Un + (size_t)r0 * 64);
        floatx4* dst = (floatx4*)us;
#pragma unroll
        for (int i = 0; i < 4; ++i) dst[tid * 4 + i] = src[tid * 4 + i];
    }
    __syncthreads();

    for (int row = 0; row < 64; ++row) {
        const floatx4* ur = (const floatx4*)(us + row * 64);
        float a0 = 0.f, a1 = 0.f;
#pragma unroll
        for (int j = 0; j < 16; ++j) {
            floatx4 u = ur[j];
            a0 = fmaf(u.x, w0[4 * j + 0], a0); a1 = fmaf(u.x, w1[4 * j + 0], a1);
            a0 = fmaf(u.y, w0[4 * j + 1], a0); a1 = fmaf(u.y, w1[4 * j + 1], a1);
            a0 = fmaf(u.z, w0[4 * j + 2], a0); a1 = fmaf(u.z, w1[4 * j + 2], a1);
            a0 = fmaf(u.w, w0[4 * j + 3], a0); a1 = fmaf(u.w, w1[4 * j + 3], a1);
        }
        float* op = out + (size_t)(r0 + row) * HD_ + c0;
        op[0]   = a0;
        op[256] = a1;
    }
}

extern "C" void kernel_launch(void* const* d_in, const int* in_sizes, int n_in,
                              void* d_out, int out_size, void* d_ws, size_t ws_size,
                              hipStream_t stream) {
    const float* x = (const float*)d_in[0];
    const float* W = (const float*)d_in[1];
    float* out = (float*)d_out;

    float* M  = (float*)d_ws;                 // 64*64
    float* y  = M + 4096;                     // 32768*64
    float* Un = y + (size_t)32768 * 64;       // 32768*64   (~16.8 MB total)

    k_M    <<<dim3(64),   64,  0, stream>>>(W, M);
    k_y    <<<dim3(256),  256, 0, stream>>>(x, M, y);
    k_attn4<<<dim3(512),  512, 0, stream>>>(x, y, Un);
    k_out  <<<dim3(1024), 256, 0, stream>>>(Un, W, out);
}

// Round 4
// 232.385 us; speedup vs baseline: 1.6847x; 1.1388x over previous
//
#include <hip/hip_runtime.h>
#include <math.h>

#define B_ 16
#define S_ 2048
#define DM_ 64
#define HD_ 1024

typedef float floatx4 __attribute__((ext_vector_type(4)));
typedef short bf16x8 __attribute__((ext_vector_type(8)));
typedef unsigned short ushort4v __attribute__((ext_vector_type(4)));
typedef unsigned short ushort8v __attribute__((ext_vector_type(8)));

// ---------------------------------------------------------------------------
// Algebraic refactor (unchanged):
//   logits = (x Wq)(x Wk)^T = x M x^T,  M = Wq Wk^T (64x64)
//   out    = softmax(mask(logits/4)) @ (x Wv) = (P @ x) @ Wv
//
// R3 (resubmit after broker timeout): 4 kernels -> 2.
//   * k_prep packs M and Wv as FRAG-LINEAR split-bf16 tables in ws
//     (B-frag order ((ct*2+kc)*64+lane)*8+j) -> B-operand loads are single
//     coalesced 16B/lane global loads from L2-resident tables.
//   * k_fused prologue: y_tile = xq @ M via MFMA (half A's key-tile 0 IS the
//     q-row tile, already staged in LDS; all 8 waves, 3-term).
//   * k_fused epilogue: out_tile = Un @ Wv via MFMA (Un merged -> split bf16
//     hi/lo in LDS, never touches global; 3-term; C-frags stored fp32).
// y and Un global round-trips (33 MB) and 2 kernel launches are gone.
// Attention interior (QK 3-term, softmax in C-frag layout, wave-private P,
// PX 2-term, split-K halves + flash merge) unchanged from R2 (verified).
// ---------------------------------------------------------------------------

__device__ __forceinline__ unsigned short bf_hi(float f) {
    return (unsigned short)((__float_as_uint(f) + 0x8000u) >> 16);   // RNE-ish
}
__device__ __forceinline__ float bf_f(unsigned short h) {
    return __uint_as_float((unsigned)h << 16);
}
__device__ __forceinline__ void cvt4(floatx4 v, ushort4v& h, ushort4v& l) {
    h[0] = bf_hi(v.x); l[0] = bf_hi(v.x - bf_f(h[0]));
    h[1] = bf_hi(v.y); l[1] = bf_hi(v.y - bf_f(h[1]));
    h[2] = bf_hi(v.z); l[2] = bf_hi(v.z - bf_f(h[2]));
    h[3] = bf_hi(v.w); l[3] = bf_hi(v.w - bf_f(h[3]));
}

#define MFMA(a, b, c) __builtin_amdgcn_mfma_f32_16x16x32_bf16((a), (b), (c), 0, 0, 0)

// frag-linear index for a B operand element (k, col):
//   ct=col>>4, lm=col&15, kc=k>>5, lg=(k>>3)&3, j=k&7
//   idx = ((ct*2+kc)*64 + 16*lg+lm)*8 + j
__device__ __forceinline__ int fragidx(int k, int col) {
    return (((col >> 4) * 2 + (k >> 5)) * 64 + ((k >> 3) & 3) * 16 + (col & 15)) * 8
           + (k & 7);
}

// K1: prep. blocks 0..63: M row d -> frag-linear split bf16 (Mf).
//           blocks 64..79: Wv -> frag-linear split bf16 (Wf).
// ws layout (shorts): Mfh[4096] Mfl[4096] Wfh[65536] Wfl[65536]
__global__ void k_prep(const float* __restrict__ W, unsigned short* __restrict__ ws) {
    unsigned short* Mfh = ws;
    unsigned short* Mfl = ws + 4096;
    unsigned short* Wfh = ws + 8192;
    unsigned short* Wfl = ws + 73728;
    const int bid = blockIdx.x, t = threadIdx.x;
    if (bid < 64) {
        const int d = bid;           // k-axis of y = x@M
        const int e = t;             // col
        const floatx4* wq = (const floatx4*)(W + (size_t)d * 3072);
        const floatx4* wk = (const floatx4*)(W + (size_t)e * 3072 + 1024);
        floatx4 a = {0.f, 0.f, 0.f, 0.f};
#pragma unroll 4
        for (int j = 0; j < 256; ++j) {
            floatx4 qv = wq[j], kv = wk[j];
            a.x = fmaf(qv.x, kv.x, a.x);
            a.y = fmaf(qv.y, kv.y, a.y);
            a.z = fmaf(qv.z, kv.z, a.z);
            a.w = fmaf(qv.w, kv.w, a.w);
        }
        const float v = (a.x + a.y) + (a.z + a.w);
        const int idx = fragidx(d, e);
        const unsigned short hv = bf_hi(v);
        Mfh[idx] = hv;
        Mfl[idx] = bf_hi(v - bf_f(hv));
    } else {
        const int col = (bid - 64) * 64 + t;   // 0..1023, lanes coalesced
#pragma unroll 8
        for (int k = 0; k < 64; ++k) {
            const float v = W[(size_t)k * 3072 + 2048 + col];
            const int idx = fragidx(k, col);
            const unsigned short hv = bf_hi(v);
            Wfh[idx] = hv;
            Wfl[idx] = bf_hi(v - bf_f(hv));
        }
    }
}

__device__ __forceinline__ void stage_tile(
        unsigned short* xrh, unsigned short* xrl,
        unsigned short* xth, unsigned short* xtl,
        int kg, int dc, floatx4 v0, floatx4 v1, floatx4 v2, floatx4 v3) {
    ushort4v h0, l0, h1, l1, h2, l2, h3, l3;
    cvt4(v0, h0, l0); cvt4(v1, h1, l1);
    cvt4(v2, h2, l2); cvt4(v3, h3, l3);
    // xr[key][d]: b64 conflict-free
    *(ushort4v*)(xrh + (4 * kg + 0) * 72 + 4 * dc) = h0;
    *(ushort4v*)(xrh + (4 * kg + 1) * 72 + 4 * dc) = h1;
    *(ushort4v*)(xrh + (4 * kg + 2) * 72 + 4 * dc) = h2;
    *(ushort4v*)(xrh + (4 * kg + 3) * 72 + 4 * dc) = h3;
    *(ushort4v*)(xrl + (4 * kg + 0) * 72 + 4 * dc) = l0;
    *(ushort4v*)(xrl + (4 * kg + 1) * 72 + 4 * dc) = l1;
    *(ushort4v*)(xrl + (4 * kg + 2) * 72 + 4 * dc) = l2;
    *(ushort4v*)(xrl + (4 * kg + 3) * 72 + 4 * dc) = l3;
    // xt[d][key]: in-reg 4x4 transpose; 16B-block XOR swizzle on col
#pragma unroll
    for (int e = 0; e < 4; ++e) {
        ushort4v th = {h0[e], h1[e], h2[e], h3[e]};
        ushort4v tl = {l0[e], l1[e], l2[e], l3[e]};
        const int rT  = 4 * dc + e;
        const int off = rT * 72 + (((kg >> 1) ^ ((rT >> 3) & 3)) << 3)
                      + ((kg & 1) << 2);
        *(ushort4v*)(xth + off) = th;
        *(ushort4v*)(xtl + off) = tl;
    }
}

// K2: fused y-GEMM + flash attention + out-GEMM.
// 512 thr = 2 split-K halves of 4 waves; wave w (in half) owns q rows 16w..+15.
__global__ __launch_bounds__(512, 1) void k_fused(
        const float* __restrict__ xg, const unsigned short* __restrict__ wsf,
        float* __restrict__ out) {
    // shorts: per half {xrh,xrl,xth,xtl}[64][72] + P 4x[16][72]; shared yh,yl.
    __shared__ __align__(16) unsigned short sm[55296];   // 110,592 B

    const int tid  = threadIdx.x;
    const int h    = tid >> 8;
    const int lt   = tid & 255;
    const int w    = lt >> 6;            // wave in half 0..3
    const int wid  = tid >> 6;           // wave in block 0..7
    const int lane = tid & 63;
    const int lm   = lane & 15;
    const int lg   = lane >> 4;

    const int bid = blockIdx.x;
    const int qt  = bid >> 4;            // heavy-first
    const int bb  = bid & 15;
    const int q0  = qt * 64;
    const int T   = 32 - qt;
    const int nA  = (T + 1) >> 1;
    const int nOwn = h ? (T - nA) : nA;
    const int kt0  = q0 + (h ? nA * 64 : 0);

    unsigned short* base = sm + h * 23040;
    unsigned short* xrh = base;
    unsigned short* xrl = base + 4608;
    unsigned short* xth = base + 9216;
    unsigned short* xtl = base + 13824;
    unsigned short* Pw  = base + 18432 + w * 1152;
    unsigned short* yh  = sm + 46080;
    unsigned short* yl  = sm + 50688;

    const unsigned short* Mfh = wsf;
    const unsigned short* Mfl = wsf + 4096;
    const unsigned short* Wfh = wsf + 8192;
    const unsigned short* Wfl = wsf + 73728;

    const float* xb = xg + (size_t)bb * S_ * 64;
    const int kg = lt >> 4, dc = lt & 15;   // staging roles

    // ---- load + stage tile 0 (both halves), then prefetch tile 1 ----
    floatx4 v0, v1, v2, v3;
    if (0 < nOwn) {
        const float* sp = xb + (size_t)(kt0 + kg * 4) * 64 + dc * 4;
        v0 = *(const floatx4*)(sp);
        v1 = *(const floatx4*)(sp + 64);
        v2 = *(const floatx4*)(sp + 128);
        v3 = *(const floatx4*)(sp + 192);
        stage_tile(xrh, xrl, xth, xtl, kg, dc, v0, v1, v2, v3);
    }
    if (1 < nOwn) {
        const float* sp = xb + (size_t)(kt0 + 64 + kg * 4) * 64 + dc * 4;
        v0 = *(const floatx4*)(sp);
        v1 = *(const floatx4*)(sp + 64);
        v2 = *(const floatx4*)(sp + 128);
        v3 = *(const floatx4*)(sp + 192);
    }
    __syncthreads();   // tile 0 visible (half A's tile 0 = q-row tile)

    // ---- y-GEMM: y = xq @ M, 3-term split, all 8 waves ----
    // wave wid: row-tile rt=wid&3, col-tiles {2*(wid>>2), 2*(wid>>2)+1}
    {
        const int rt = wid & 3;
        const int cp = wid >> 2;
        bf16x8 axh[2], axl[2];
#pragma unroll
        for (int kc = 0; kc < 2; ++kc) {
            const int off = (16 * rt + lm) * 72 + 32 * kc + 8 * lg;
            axh[kc] = *(const bf16x8*)(sm + off);          // xrh of half A
            axl[kc] = *(const bf16x8*)(sm + 4608 + off);   // xrl of half A
        }
#pragma unroll
        for (int cc = 0; cc < 2; ++cc) {
            const int ct = cp * 2 + cc;
            floatx4 yC = {0.f, 0.f, 0.f, 0.f};
#pragma unroll
            for (int kc = 0; kc < 2; ++kc) {
                bf16x8 bh = *(const bf16x8*)(Mfh + ((ct * 2 + kc) * 64 + lane) * 8);
                bf16x8 bl = *(const bf16x8*)(Mfl + ((ct * 2 + kc) * 64 + lane) * 8);
                yC = MFMA(axh[kc], bh, yC);
                yC = MFMA(axh[kc], bl, yC);
                yC = MFMA(axl[kc], bh, yC);
            }
#pragma unroll
            for (int r = 0; r < 4; ++r) {
                const float vv = yC[r];
                const unsigned short hv = bf_hi(vv);
                const int o = (16 * rt + 4 * lg + r) * 72 + ct * 16 + lm;
                yh[o] = hv;
                yl[o] = bf_hi(vv - bf_f(hv));
            }
        }
    }
    __syncthreads();   // y visible

    // hoist y A-frags (loop-invariant): rows 16w+lm
    bf16x8 aqh[2], aql[2];
#pragma unroll
    for (int kc = 0; kc < 2; ++kc) {
        const int off = (16 * w + lm) * 72 + 32 * kc + 8 * lg;
        aqh[kc] = *(const bf16x8*)(yh + off);
        aql[kc] = *(const bf16x8*)(yl + off);
    }

    floatx4 U[4];                 // U[c][r] = U[q=4lg+r][d=lm+16c]
    float m[4], lsum[4];
#pragma unroll
    for (int r = 0; r < 4; ++r) { m[r] = -INFINITY; lsum[r] = 0.f; }
#pragma unroll
    for (int c = 0; c < 4; ++c) U[c] = (floatx4){0.f, 0.f, 0.f, 0.f};

    for (int t = 0; t < nA; ++t) {
        const int kt = kt0 + t * 64;
        if (t < nOwn) {
            // ---- QK: 3-term split, 24 mfma ----
            floatx4 Sc[4] = {{0.f,0.f,0.f,0.f},{0.f,0.f,0.f,0.f},
                             {0.f,0.f,0.f,0.f},{0.f,0.f,0.f,0.f}};
#pragma unroll
            for (int kc = 0; kc < 2; ++kc) {
#pragma unroll
                for (int c = 0; c < 4; ++c) {
                    const int ro = (lm + 16 * c) * 72 + 32 * kc + 8 * lg;
                    bf16x8 bh = *(const bf16x8*)(xrh + ro);
                    bf16x8 bl = *(const bf16x8*)(xrl + ro);
                    Sc[c] = MFMA(aqh[kc], bh, Sc[c]);
                    Sc[c] = MFMA(aqh[kc], bl, Sc[c]);
                    Sc[c] = MFMA(aql[kc], bh, Sc[c]);
                }
            }

            // ---- scale + faithful mask + online softmax ----
            float p[4][4], alpha[4];
#pragma unroll
            for (int r = 0; r < 4; ++r) {
                const int ig = q0 + 16 * w + 4 * lg + r;
                float sv[4];
                float rmax = -INFINITY;
#pragma unroll
                for (int c = 0; c < 4; ++c) {
                    const int jg = kt + lm + 16 * c;
                    float v = Sc[c][r] * 0.25f;
                    if (jg < ig || v == 0.0f) v = -9.0e15f;   // triu + (==0 -> -9e15)
                    sv[c] = v;
                    rmax = fmaxf(rmax, v);
                }
                rmax = fmaxf(rmax, __shfl_xor(rmax, 1));
                rmax = fmaxf(rmax, __shfl_xor(rmax, 2));
                rmax = fmaxf(rmax, __shfl_xor(rmax, 4));
                rmax = fmaxf(rmax, __shfl_xor(rmax, 8));
                const float mnew = fmaxf(m[r], rmax);
                alpha[r] = __expf(m[r] - mnew);               // first tile: 0
                float ps = 0.f;
#pragma unroll
                for (int c = 0; c < 4; ++c) {
                    const float pv = __expf(sv[c] - mnew);
                    p[r][c] = pv;
                    ps += pv;
                }
                m[r] = mnew;
                lsum[r] = lsum[r] * alpha[r] + ps;            // per-lane partial
            }

            // P -> per-wave LDS (bf16 hi)
#pragma unroll
            for (int r = 0; r < 4; ++r)
#pragma unroll
                for (int c = 0; c < 4; ++c)
                    Pw[(4 * lg + r) * 72 + lm + 16 * c] = bf_hi(p[r][c]);

            // rescale U
            floatx4 av = {alpha[0], alpha[1], alpha[2], alpha[3]};
#pragma unroll
            for (int c = 0; c < 4; ++c) U[c] *= av;

            // ---- PX: 2-term, 16 mfma (P wave-private: no barrier) ----
#pragma unroll
            for (int kc = 0; kc < 2; ++kc) {
                bf16x8 ap = *(const bf16x8*)(Pw + lm * 72 + 32 * kc + 8 * lg);
#pragma unroll
                for (int c = 0; c < 4; ++c) {
                    const int d   = lm + 16 * c;
                    const int blk = (4 * kc + lg) ^ ((d >> 3) & 3);
                    const int off = d * 72 + blk * 8;
                    bf16x8 bh = *(const bf16x8*)(xth + off);
                    bf16x8 bl = *(const bf16x8*)(xtl + off);
                    U[c] = MFMA(ap, bh, U[c]);
                    U[c] = MFMA(ap, bl, U[c]);
                }
            }
        }

        if (t + 1 < nA) {
            __syncthreads();   // readers done with tile t buffers
            if (t + 1 < nOwn)
                stage_tile(xrh, xrl, xth, xtl, kg, dc, v0, v1, v2, v3);
            if (t + 2 < nOwn) {
                const float* sp = xb + (size_t)(kt + 128 + kg * 4) * 64 + dc * 4;
                v0 = *(const floatx4*)(sp);
                v1 = *(const floatx4*)(sp + 64);
                v2 = *(const floatx4*)(sp + 128);
                v3 = *(const floatx4*)(sp + 192);
            }
            __syncthreads();   // tile t+1 visible
        }
    }

    // ---- finalize per-half l ----
    float lf[4];
#pragma unroll
    for (int r = 0; r < 4; ++r) {
        float s2 = lsum[r];
        s2 += __shfl_xor(s2, 1);
        s2 += __shfl_xor(s2, 2);
        s2 += __shfl_xor(s2, 4);
        s2 += __shfl_xor(s2, 8);
        lf[r] = s2;
    }

    // ---- merge halves; half A writes Un (split bf16) into LDS ----
    __syncthreads();                       // all compute done; buffers free
    float* sc = (float*)sm;                // 256*24 floats (overlaps half-A x)
    unsigned short* Unh = sm + 23040;      // half-B xrh region
    unsigned short* Unl = sm + 27648;      // half-B xrl region
    if (h == 1) {
        float* bp = sc + lt * 24;
        *(floatx4*)(bp)     = (floatx4){m[0], m[1], m[2], m[3]};
        *(floatx4*)(bp + 4) = (floatx4){lf[0], lf[1], lf[2], lf[3]};
#pragma unroll
        for (int c = 0; c < 4; ++c) *(floatx4*)(bp + 8 + 4 * c) = U[c];
    }
    __syncthreads();
    if (h == 0) {
        const float* bp = sc + lt * 24;
        floatx4 mB = *(const floatx4*)(bp);
        floatx4 lB = *(const floatx4*)(bp + 4);
        floatx4 UB[4];
#pragma unroll
        for (int c = 0; c < 4; ++c) UB[c] = *(const floatx4*)(bp + 8 + 4 * c);
        float eA[4], eB[4], inv[4];
#pragma unroll
        for (int r = 0; r < 4; ++r) {
            const float mT = fmaxf(m[r], mB[r]);   // m finite (A has tile 0)
            eA[r] = __expf(m[r] - mT);
            eB[r] = __expf(mB[r] - mT);            // empty B: exp(-inf)=0
            const float lT = lf[r] * eA[r] + lB[r] * eB[r];
            inv[r] = 1.0f / lT;
        }
#pragma unroll
        for (int r = 0; r < 4; ++r)
#pragma unroll
            for (int c = 0; c < 4; ++c) {
                const float o = (U[c][r] * eA[r] + UB[c][r] * eB[r]) * inv[r];
                const unsigned short hv = bf_hi(o);
                const int oo = (16 * w + 4 * lg + r) * 72 + lm + 16 * c;
                Unh[oo] = hv;
                Unl[oo] = bf_hi(o - bf_f(hv));
            }
    }
    __syncthreads();   // Un visible

    // ---- out-GEMM: out = Un @ Wv, 3-term, all 8 waves ----
    // wave wid: cols [128*wid, 128*wid+128) = 8 col-tiles; 4 row-tiles.
    bf16x8 Ah[4][2], Al[4][2];
#pragma unroll
    for (int rt = 0; rt < 4; ++rt)
#pragma unroll
        for (int kc = 0; kc < 2; ++kc) {
            const int off = (16 * rt + lm) * 72 + 32 * kc + 8 * lg;
            Ah[rt][kc] = *(const bf16x8*)(Unh + off);
            Al[rt][kc] = *(const bf16x8*)(Unl + off);
        }
    const size_t orow0 = (size_t)bb * S_ + q0;
#pragma unroll
    for (int ctl = 0; ctl < 8; ++ctl) {
        const int ct = wid * 8 + ctl;
        bf16x8 Bh0 = *(const bf16x8*)(Wfh + ((ct * 2 + 0) * 64 + lane) * 8);
        bf16x8 Bl0 = *(const bf16x8*)(Wfl + ((ct * 2 + 0) * 64 + lane) * 8);
        bf16x8 Bh1 = *(const bf16x8*)(Wfh + ((ct * 2 + 1) * 64 + lane) * 8);
        bf16x8 Bl1 = *(const bf16x8*)(Wfl + ((ct * 2 + 1) * 64 + lane) * 8);
#pragma unroll
        for (int rt = 0; rt < 4; ++rt) {
            floatx4 C = {0.f, 0.f, 0.f, 0.f};
            C = MFMA(Ah[rt][0], Bh0, C);
            C = MFMA(Ah[rt][0], Bl0, C);
            C = MFMA(Al[rt][0], Bh0, C);
            C = MFMA(Ah[rt][1], Bh1, C);
            C = MFMA(Ah[rt][1], Bl1, C);
            C = MFMA(Al[rt][1], Bh1, C);
#pragma unroll
            for (int r = 0; r < 4; ++r)
                out[(orow0 + 16 * rt + 4 * lg + r) * HD_ + ct * 16 + lm] = C[r];
        }
    }
}

extern "C" void kernel_launch(void* const* d_in, const int* in_sizes, int n_in,
                              void* d_out, int out_size, void* d_ws, size_t ws_size,
                              hipStream_t stream) {
    const float* x = (const float*)d_in[0];
    const float* W = (const float*)d_in[1];
    unsigned short* wsf = (unsigned short*)d_ws;   // 139,264 shorts = 272 KB

    k_prep <<<dim3(80),  64,  0, stream>>>(W, wsf);
    k_fused<<<dim3(512), 512, 0, stream>>>(x, wsf, (float*)d_out);
}